// Round 6
// baseline (289.327 us; speedup 1.0000x reference)
//
#include <hip/hip_runtime.h>
#include <hip/hip_bf16.h>
#include <stdint.h>
#include <stddef.h>

#define D_M   1024
#define N_H   16
#define D_K   64
#define S_LEN 2048
#define N_B   4
#define P_LEN 1792
#define M_ROWS (N_B*S_LEN)   // 8192

// 0.125 * log2(e): folds 1/sqrt(dk) and the exp->exp2 conversion into Q
#define QSCALE 0.1803368801111601f

typedef unsigned short u16;
typedef __bf16  bf16x8 __attribute__((ext_vector_type(8)));
typedef __bf16  bf16x4 __attribute__((ext_vector_type(4)));
typedef __bf16  bf16x2 __attribute__((ext_vector_type(2)));
typedef float   f32x4  __attribute__((ext_vector_type(4)));
typedef float   f32x16 __attribute__((ext_vector_type(16)));
typedef unsigned u32x4 __attribute__((ext_vector_type(4)));

#define MFMA32(a,b,c)   __builtin_amdgcn_mfma_f32_16x16x32_bf16((a),(b),(c),0,0,0)
#define MFMA3216(a,b,c) __builtin_amdgcn_mfma_f32_32x32x16_bf16((a),(b),(c),0,0,0)

__device__ __forceinline__ float ex2(float x){
#if defined(__HIP_DEVICE_COMPILE__) && __has_builtin(__builtin_amdgcn_exp2f)
  return __builtin_amdgcn_exp2f(x);
#else
  return exp2f(x);
#endif
}

#define GLDS16(gp, lp) __builtin_amdgcn_global_load_lds( \
    (__attribute__((address_space(1))) void*)(gp), \
    (__attribute__((address_space(3))) void*)(lp), 16, 0, 0)

__device__ __forceinline__ u16 f2bf(float f){
  unsigned u = __builtin_bit_cast(unsigned, f);
  u += 0x7FFFu + ((u>>16)&1u);     // RNE round to bf16
  return (u16)(u>>16);
}

__device__ __forceinline__ unsigned pkbf(float a, float b){
  bf16x2 t; t[0] = (__bf16)a; t[1] = (__bf16)b;
  return __builtin_bit_cast(unsigned, t);   // compiler emits v_cvt_pk_bf16_f32
}

// v_permlane32_swap_b32: x = [x_lo | y_lo_old], y = [x_hi_old | y_hi]. (gfx950)
__device__ __forceinline__ void plswap(unsigned &x, unsigned &y){
  asm("v_permlane32_swap_b32 %0, %1" : "+v"(x), "+v"(y));
}

// ---------------- fp32 -> bf16 convert (vectorized, 8 elems/thread/iter) ----
__global__ void cvt_bf16(const float* __restrict__ in, u16* __restrict__ out, int n8){
  typedef u16 u16x8 __attribute__((ext_vector_type(8)));
  for (int i = blockIdx.x*blockDim.x + threadIdx.x; i < n8; i += gridDim.x*blockDim.x){
    const float4* p = (const float4*)(in + (size_t)i*8);
    float4 a = p[0], b = p[1];
    u16x8 o;
    o[0]=f2bf(a.x); o[1]=f2bf(a.y); o[2]=f2bf(a.z); o[3]=f2bf(a.w);
    o[4]=f2bf(b.x); o[5]=f2bf(b.y); o[6]=f2bf(b.z); o[7]=f2bf(b.w);
    *(u16x8*)(out + (size_t)i*8) = o;
  }
}

// ---------------- 128x128 bf16 NT GEMM (C = (A*B^T + bias)*scale), m97 ------
// MODE 0: out bf16 (B,H,S,dk) head-split       (Q / K projections)
// MODE 1: out bf16 (B,H,dk,S) head-split, transposed   (V projection)
// MODE 2: out fp32 (M,N) row-major             (output projection -> d_out)
template<int MODE>
__global__ __launch_bounds__(256,2)
void gemm_bt(const u16* __restrict__ A, const u16* __restrict__ Bm,
             const float* __restrict__ bias, void* __restrict__ Cout, float scale)
{
  constexpr int Kd = 1024, N = 1024;
  __shared__ __align__(16) u16 As[128*32];
  __shared__ __align__(16) u16 Bs[128*32];
  const int tid  = threadIdx.x;
  const int wid  = tid >> 6, lane = tid & 63;
  const int rowBase = blockIdx.x * 128, colBase = blockIdx.y * 128;

  const int srow = (wid<<4) + (lane>>2);
  const int scol = (lane&3) << 3;
  const u16* Ag0 = A  + (size_t)(rowBase + srow)*Kd + scol;
  const u16* Ag1 = Ag0 + (size_t)64*Kd;
  const u16* Bg0 = Bm + (size_t)(colBase + srow)*Kd + scol;
  const u16* Bg1 = Bg0 + (size_t)64*Kd;
  u16* AsW0 = As + (wid<<9);
  u16* AsW1 = As + 2048 + (wid<<9);
  u16* BsW0 = Bs + (wid<<9);
  u16* BsW1 = Bs + 2048 + (wid<<9);

  f32x4 acc[4][4] = {};
  const int fr = lane & 15, fk = (lane>>4) << 3;
  const int wr = (wid>>1) << 6, wc = (wid&1) << 6;

  for (int kt = 0; kt < Kd/32; ++kt){
    __syncthreads();
    const int ko = kt*32;
    GLDS16(Ag0+ko, AsW0); GLDS16(Ag1+ko, AsW1);
    GLDS16(Bg0+ko, BsW0); GLDS16(Bg1+ko, BsW1);
    __syncthreads();
    bf16x8 af[4], bf[4];
#pragma unroll
    for (int i=0;i<4;++i) af[i] = *(const bf16x8*)&As[(wr + i*16 + fr)*32 + fk];
#pragma unroll
    for (int i=0;i<4;++i) bf[i] = *(const bf16x8*)&Bs[(wc + i*16 + fr)*32 + fk];
#pragma unroll
    for (int i=0;i<4;++i)
#pragma unroll
      for (int j=0;j<4;++j)
        acc[i][j] = MFMA32(af[i], bf[j], acc[i][j]);
  }

  const int rr0 = (lane>>4) << 2;
#pragma unroll
  for (int i=0;i<4;++i){
#pragma unroll
    for (int j=0;j<4;++j){
      const int gc = colBase + wc + j*16 + fr;
      const float bb = bias[gc];
#pragma unroll
      for (int r=0;r<4;++r){
        const int gr = rowBase + wr + i*16 + rr0 + r;
        const float v = (acc[i][j][r] + bb) * scale;
        if (MODE == 2){
          ((float*)Cout)[(size_t)gr*N + gc] = v;
        } else {
          const int b = gr >> 11, s = gr & 2047;
          const int h = gc >> 6,  k = gc & 63;
          if (MODE == 0)
            ((u16*)Cout)[(((size_t)(b*N_H + h))*S_LEN + s)*D_K + k] = f2bf(v);
          else
            ((u16*)Cout)[(((size_t)(b*N_H + h))*D_K + k)*S_LEN + s] = f2bf(v);
        }
      }
    }
  }
}

// ---------------- attention (balanced units, 64-key pipelined steps) ---------
// Lane: q-col = lane&31, half h = lane>>5. Swapped QK^T via 32x32x16 MFMA:
// lane holds 16 k-rows of S^T per subtile: k = ks + (r&3)+8*(r>>2)+4h.
// P^T -> PV B-frag: 8 cvt_pk + 4 permlane32_swap per subtile (T12).
// PV: A = V^T rows, B = P^T -> O^T in 2x f32x16.  Softmax denominator l is a
// third MFMA accumulator (A = ones): leaves the per-step serial chain.

__device__ __forceinline__ void kload_pair(bf16x8* kr, const u16* __restrict__ Kb,
                                           int ks, int q, int h){
  int ks2 = ks + 32; if (ks2 > S_LEN-32) ks2 = S_LEN-32;   // clamp (values unused)
  const u16* kp0 = Kb + (size_t)(ks  + q)*D_K + (h<<3);
  const u16* kp1 = Kb + (size_t)(ks2 + q)*D_K + (h<<3);
#pragma unroll
  for (int kb=0;kb<4;++kb){
    kr[kb]   = *(const bf16x8*)(kp0 + 16*kb);
    kr[4+kb] = *(const bf16x8*)(kp1 + 16*kb);
  }
}

// NS: #32-key subtiles (1 or 2). M0/M1 masks: 0 none, 1 causal (k>qg), 2 diag.
// PRE: prefetch next K pair at ksn into kr (after QK consumes current).
template<bool PRE, int NS, int M0, int M1>
__device__ __forceinline__ void attn_step(
    const u16* __restrict__ Kb, const u16* __restrict__ Vb,
    bf16x8* kr, const bf16x8* qf, bf16x8 ones,
    int ks0, int ks1, int ksn,
    int qg, int h, int q,
    float& m, f32x16& o0, f32x16& o1, f32x16& o2)
{
  // ---- QK^T (swapped): two independent accumulator chains
  f32x16 s0 = {}, s1 = {};
  __builtin_amdgcn_s_setprio(1);
#pragma unroll
  for (int kb=0;kb<4;++kb){
    s0 = MFMA3216(kr[kb], qf[kb], s0);
    if (NS==2) s1 = MFMA3216(kr[4+kb], qf[kb], s1);
  }
  __builtin_amdgcn_s_setprio(0);

  // ---- issue V loads now; consumed after softmax (~250 cyc of cover)
  bf16x8 v0[4], v1[4];
  {
    const u16* vp0 = Vb + (size_t)q*S_LEN + ks0 + (h<<3);
#pragma unroll
    for (int db=0;db<2;++db){
      v0[2*db]   = *(const bf16x8*)(vp0 + (size_t)(32*db)*S_LEN);
      v0[2*db+1] = *(const bf16x8*)(vp0 + (size_t)(32*db)*S_LEN + 16);
    }
    if (NS==2){
      const u16* vp1 = Vb + (size_t)q*S_LEN + ks1 + (h<<3);
#pragma unroll
      for (int db=0;db<2;++db){
        v1[2*db]   = *(const bf16x8*)(vp1 + (size_t)(32*db)*S_LEN);
        v1[2*db+1] = *(const bf16x8*)(vp1 + (size_t)(32*db)*S_LEN + 16);
      }
    }
  }
  // ---- prefetch next K pair (hidden under softmax)
  if (PRE) kload_pair(kr, Kb, ksn, q, h);

  // ---- masks
  if (M0 != 0){
#pragma unroll
    for (int r=0;r<16;++r){
      const int krow = (r&3) + 8*(r>>2) + 4*h;
      if (M0==1){ if (ks0 + krow > qg) s0[r] = -1e30f; }
      if (M0==2){ if (krow != q)       s0[r] = -1e30f; }
    }
  }
  if (NS==2 && M1 != 0){
#pragma unroll
    for (int r=0;r<16;++r){
      const int krow = (r&3) + 8*(r>>2) + 4*h;
      if (M1==1){ if (ks1 + krow > qg) s1[r] = -1e30f; }
      if (M1==2){ if (krow != q)       s1[r] = -1e30f; }
    }
  }

  // ---- max: pairwise fold + max3-friendly tree + one cross-half shfl
  float t[16];
#pragma unroll
  for (int r=0;r<16;++r) t[r] = (NS==2) ? fmaxf(s0[r], s1[r]) : s0[r];
  float u0 = fmaxf(fmaxf(t[0], t[1]), t[2]);
  float u1 = fmaxf(fmaxf(t[3], t[4]), t[5]);
  float u2 = fmaxf(fmaxf(t[6], t[7]), t[8]);
  float u3 = fmaxf(fmaxf(t[9], t[10]), t[11]);
  float u4 = fmaxf(fmaxf(t[12], t[13]), t[14]);
  float tm = fmaxf(fmaxf(fmaxf(u0, u1), fmaxf(u2, u3)), fmaxf(u4, t[15]));
  tm = fmaxf(tm, __shfl_xor(tm, 32, 64));

  const bool skip = __all(tm <= m);     // defer rescale when max didn't grow
  const float mn = skip ? m : fmaxf(m, tm);

  if (!skip){
    const float alpha = ex2(m - mn);
    m = mn;
#pragma unroll
    for (int r=0;r<16;++r){ o0[r] *= alpha; o1[r] *= alpha; o2[r] *= alpha; }
  }

  // ---- exp2 (trans pipe; no sum tree — l rides the MFMA pipe via ones-row)
#pragma unroll
  for (int r=0;r<16;++r){
    s0[r] = ex2(s0[r] - mn);
    if (NS==2) s1[r] = ex2(s1[r] - mn);
  }

  // ---- pack P^T into PV B-fragments (cvt_pk + permlane32_swap)
  unsigned w0[8];
#pragma unroll
  for (int i=0;i<8;++i) w0[i] = pkbf(s0[2*i], s0[2*i+1]);
  plswap(w0[0],w0[2]); plswap(w0[1],w0[3]);
  plswap(w0[4],w0[6]); plswap(w0[5],w0[7]);
  bf16x8 p00 = __builtin_bit_cast(bf16x8, (u32x4){w0[0],w0[1],w0[2],w0[3]});
  bf16x8 p01 = __builtin_bit_cast(bf16x8, (u32x4){w0[4],w0[5],w0[6],w0[7]});
  bf16x8 p10, p11;
  if (NS==2){
    unsigned w1[8];
#pragma unroll
    for (int i=0;i<8;++i) w1[i] = pkbf(s1[2*i], s1[2*i+1]);
    plswap(w1[0],w1[2]); plswap(w1[1],w1[3]);
    plswap(w1[4],w1[6]); plswap(w1[5],w1[7]);
    p10 = __builtin_bit_cast(bf16x8, (u32x4){w1[0],w1[1],w1[2],w1[3]});
    p11 = __builtin_bit_cast(bf16x8, (u32x4){w1[4],w1[5],w1[6],w1[7]});
  }

  // ---- PV + denominator: three accumulator chains
  __builtin_amdgcn_s_setprio(1);
  o0 = MFMA3216(v0[0], p00, o0);
  o1 = MFMA3216(v0[2], p00, o1);
  o2 = MFMA3216(ones,  p00, o2);
  o0 = MFMA3216(v0[1], p01, o0);
  o1 = MFMA3216(v0[3], p01, o1);
  o2 = MFMA3216(ones,  p01, o2);
  if (NS==2){
    o0 = MFMA3216(v1[0], p10, o0);
    o1 = MFMA3216(v1[2], p10, o1);
    o2 = MFMA3216(ones,  p10, o2);
    o0 = MFMA3216(v1[1], p11, o0);
    o1 = MFMA3216(v1[3], p11, o1);
    o2 = MFMA3216(ones,  p11, o2);
  }
  __builtin_amdgcn_s_setprio(0);
}

// One q-tile run. TAIL: 1 = causal tail (prefix), 2 = self-diag tail (cand).
template<int TAIL>
__device__ __forceinline__ void attn_run(
    const u16* __restrict__ Q, const u16* __restrict__ Kb,
    const u16* __restrict__ Vb, u16* __restrict__ ctx,
    int bh, int qbase, int nfull, int h, int q, bf16x8 ones)
{
  const int qg = qbase + q;
  const u16* Qp = Q + ((size_t)bh * S_LEN + qg) * D_K + (h<<3);
  bf16x8 qf[4];
#pragma unroll
  for (int kb=0;kb<4;++kb) qf[kb] = *(const bf16x8*)(Qp + 16*kb);
  float m = -1e30f;
  f32x16 o0 = {}, o1 = {}, o2 = {};

  const int npair = nfull >> 1;
  const int kst = (TAIL==2) ? qbase : npair*64;   // tail / remainder position
  bf16x8 kr[8];
  kload_pair(kr, Kb, 0, q, h);
  int ks = 0;
  for (int p=0; p<npair; ++p, ks+=64){
    const int ksn = (p+1 < npair) ? ks+64 : kst;
    attn_step<true,2,0,0>(Kb, Vb, kr, qf, ones, ks, ks+32, ksn, qg, h, q, m, o0, o1, o2);
  }
  if (TAIL==2)
    attn_step<false,1,2,0>(Kb, Vb, kr, qf, ones, kst, 0, 0, qg, h, q, m, o0, o1, o2);
  else if (nfull & 1)   // remainder full tile + causal diagonal tile
    attn_step<false,2,0,1>(Kb, Vb, kr, qf, ones, kst, kst+32, 0, qg, h, q, m, o0, o1, o2);
  else                  // causal diagonal tile only
    attn_step<false,1,1,0>(Kb, Vb, kr, qf, ones, kst, 0, 0, qg, h, q, m, o0, o1, o2);

  // ---- write O^T (row d = (r&3)+8*(r>>2)+4h + 32db, col q); l = o2[0]
  const int b = bh >> 4, hd = bh & 15;
  const float inv = 1.f / o2[0];
  u16* cp = ctx + ((size_t)b*S_LEN + qg)*D_M + hd*D_K;
#pragma unroll
  for (int rg=0; rg<4; ++rg){
    const int d0 = 8*rg + 4*h;
    bf16x4 oa, ob;
#pragma unroll
    for (int e=0;e<4;++e){ oa[e] = (__bf16)(o0[4*rg+e]*inv); ob[e] = (__bf16)(o1[4*rg+e]*inv); }
    *(bf16x4*)(cp + d0)      = oa;
    *(bf16x4*)(cp + 32 + d0) = ob;
  }
}

// Balanced units: per bh, 36 units of exactly 57 key-tiles:
//   u in [0,8):  candidate q-tile u  (56 full prefix tiles + self)
//   u in [8,36): prefix pair j=u-8 -> q-tiles j and 55-j ((j+1)+(56-j)=57)
// Flat grid 64*36 = 2304 one-wave blocks; mapping pins each bh to one XCD.
__global__ __launch_bounds__(64)
void attn_all(const u16* __restrict__ Q, const u16* __restrict__ K,
              const u16* __restrict__ Vt, u16* __restrict__ ctx)
{
  const int id   = blockIdx.x;
  const int xcd  = id & 7;
  const int slot = id >> 3;            // [0,288)
  const int grp  = slot / 36;
  const int u    = slot - 36*grp;
  const int bh   = xcd + (grp << 3);   // all 36 units of a bh on one XCD

  const int lane = threadIdx.x & 63;
  const int q = lane & 31, h = lane >> 5;

  const u16* Kb = K  + (size_t)bh * S_LEN * D_K;
  const u16* Vb = Vt + (size_t)bh * D_K * S_LEN;
  bf16x8 ones;
#pragma unroll
  for (int i=0;i<8;++i) ones[i] = (__bf16)1.0f;

  if (u < 8){
    attn_run<2>(Q, Kb, Vb, ctx, bh, P_LEN + 32*u, 56, h, q, ones);
  } else {
    const int j = u - 8;
    attn_run<1>(Q, Kb, Vb, ctx, bh, 32*j,      j,    h, q, ones);
    attn_run<1>(Q, Kb, Vb, ctx, bh, 32*(55-j), 55-j, h, q, ones);
  }
}

// ---------------- launcher ---------------------------------------------------
extern "C" void kernel_launch(void* const* d_in, const int* in_sizes, int n_in,
                              void* d_out, int out_size, void* d_ws, size_t ws_size,
                              hipStream_t stream)
{
  const float* query = (const float*)d_in[0];
  const float* key   = (const float*)d_in[1];
  const float* value = (const float*)d_in[2];
  const float* Wq = (const float*)d_in[3];
  const float* bq = (const float*)d_in[4];
  const float* Wk = (const float*)d_in[5];
  const float* bk = (const float*)d_in[6];
  const float* Wv = (const float*)d_in[7];
  const float* bv = (const float*)d_in[8];
  const float* Wo = (const float*)d_in[9];
  const float* bo = (const float*)d_in[10];

  if (ws_size < (size_t)(66u<<20)) return;

  char* ws = (char*)d_ws;
  u16* Xb = (u16*)(ws);                          // 16 MiB: bf16 input (reused x3), then ctx
  u16* Wb = (u16*)(ws + (16u<<20));              //  2 MiB: bf16 weight (reused x4)
  u16* Qb = (u16*)(ws + (18u<<20));              // 16 MiB: Q (B,H,S,dk), pre-scaled
  u16* Kb = (u16*)(ws + (34u<<20));              // 16 MiB: K (B,H,S,dk)
  u16* Vb = (u16*)(ws + (50u<<20));              // 16 MiB: V^T (B,H,dk,S)
  u16* ctx = Xb;

  const int nX8 = (M_ROWS*D_M)/8, nW8 = (D_M*D_M)/8;
  dim3 gg(M_ROWS/128, D_M/128);

  cvt_bf16<<<2048,256,0,stream>>>(query, Xb, nX8);
  cvt_bf16<<<512, 256,0,stream>>>(Wq,    Wb, nW8);
  gemm_bt<0><<<gg,256,0,stream>>>(Xb, Wb, bq, Qb, QSCALE);

  cvt_bf16<<<2048,256,0,stream>>>(key,   Xb, nX8);
  cvt_bf16<<<512, 256,0,stream>>>(Wk,    Wb, nW8);
  gemm_bt<0><<<gg,256,0,stream>>>(Xb, Wb, bk, Kb, 1.0f);

  cvt_bf16<<<2048,256,0,stream>>>(value, Xb, nX8);
  cvt_bf16<<<512, 256,0,stream>>>(Wv,    Wb, nW8);
  gemm_bt<1><<<gg,256,0,stream>>>(Xb, Wb, bv, Vb, 1.0f);

  attn_all<<<dim3(64*36), 64, 0, stream>>>(Qb, Kb, Vb, ctx);

  cvt_bf16<<<512,256,0,stream>>>(Wo, Wb, nW8);
  gemm_bt<2><<<gg,256,0,stream>>>(ctx, Wb, bo, (float*)d_out, 1.0f);
}